// Round 8
// baseline (368.252 us; speedup 1.0000x reference)
//
#include <hip/hip_runtime.h>

typedef __bf16 bf16;
typedef __bf16 bf16x8 __attribute__((ext_vector_type(8)));
typedef __bf16 bf16x4 __attribute__((ext_vector_type(4)));
typedef float floatx4 __attribute__((ext_vector_type(4)));

typedef __attribute__((address_space(1))) void gvoid;
typedef __attribute__((address_space(3))) void lvoid;
#define ASYNC_COPY16(gp, lp) \
  __builtin_amdgcn_global_load_lds((gvoid*)(gp), (lvoid*)(lp), 16, 0, 0)

#define NB 4
#define SQ 2048
#define DMODEL 1024
#define NH 16
#define HD 64
#define MTOK (NB * SQ)   // 8192
#define LOG2E 1.44269504088896f

// workspace layout (bytes)
#define XB_OFF 0ull                        // bf16 X       [8192][1024]  16 MB
#define WT_OFF (16ull * 1024 * 1024)       // bf16 W^T x3  [3][1024][1024] 6 MB
#define Q_OFF  (22ull * 1024 * 1024)       // bf16 Q [64][2048][64]  16 MB (pre-scaled 0.125*log2e)
#define K_OFF  (38ull * 1024 * 1024)       // bf16 K [64][2048][64]  16 MB
#define V_OFF  (54ull * 1024 * 1024)       // bf16 V^T [64][64][2048] 16 MB
#define FLG_OFF (70ull * 1024 * 1024)      // int flags [4][16][32]   8 KB

// ------------------------------------------------- prep: convert X + transpose W
__global__ __launch_bounds__(256) void prep(
    const float* __restrict__ x, bf16* __restrict__ xb,
    const float* __restrict__ w0, const float* __restrict__ w1,
    const float* __restrict__ w2, bf16* __restrict__ wt) {
  __shared__ float tlds[32][33];
  int blk = blockIdx.x;
  int t = threadIdx.x;
  if (blk < 8192) {
    int i = blk * 256 + t;
    float4 v = ((const float4*)x)[i];
    bf16x4 o;
    o[0] = (bf16)v.x; o[1] = (bf16)v.y; o[2] = (bf16)v.z; o[3] = (bf16)v.w;
    ((bf16x4*)xb)[i] = o;
  } else {
    int tidx = blk - 8192;            // 0..3071
    int z = tidx >> 10;               // 0..2
    int rem = tidx & 1023;
    int kb = ((rem >> 5) & 31) * 32, nb = (rem & 31) * 32;
    const float* w = (z == 0) ? w0 : (z == 1) ? w1 : w2;
    bf16* out = wt + (size_t)z * DMODEL * DMODEL;
    int tx = t & 31, ty = t >> 5;     // 32 x 8
#pragma unroll
    for (int i = 0; i < 4; i++)
      tlds[ty + 8 * i][tx] = w[(size_t)(kb + ty + 8 * i) * DMODEL + nb + tx];
    __syncthreads();
#pragma unroll
    for (int i = 0; i < 4; i++)
      out[(size_t)(nb + ty + 8 * i) * DMODEL + kb + tx] = (bf16)tlds[tx][ty + 8 * i];
  }
}

// ---------------------------------------------------------------- QKV GEMM + mask scan (fused)
// 3584 blocks = 64 supergroups x 56. u<24 -> gemm (1536), u>=24 -> mask (2048).
// Supergroup keeps gemm:mask co-resident; mt%8 == blockIdx%8 pins each A-tile
// row to one XCD's L2. As/Bs XOR-swizzled; Q/K accumulate transposed.
#define BK 64
__global__ __launch_bounds__(256) void qkv_mask(
    const bf16* __restrict__ xb,   // [8192][1024]
    const bf16* __restrict__ wt,   // [3][1024 n][1024 k]
    const float* __restrict__ biasq, const float* __restrict__ biask,
    const float* __restrict__ biasv,
    bf16* __restrict__ q, bf16* __restrict__ k, bf16* __restrict__ v,
    const float* __restrict__ mask, int* __restrict__ flags) {
  __shared__ bf16 As[128 * BK];
  __shared__ bf16 Bs[128 * BK];

  int idx = blockIdx.x;
  int sg = idx / 56, u = idx % 56;   // 56 % 8 == 0 -> XCD = u % 8
  int t = threadIdx.x;

  if (u >= 24) {
    // ---------------- mask tile scan
    int midx = sg * 32 + (u - 24);    // 0..2047
    int kt = midx & 31, qt = (midx >> 5) & 15, b = midx >> 9;
    const float* mb = mask + ((size_t)b * SQ + qt * 128) * SQ + kt * 64;
    int row = t >> 1, half = t & 1;
    const float4* p = (const float4*)(mb + (size_t)row * SQ + half * 32);
    bool nz = false;
#pragma unroll
    for (int i = 0; i < 8; i++) {
      float4 vv = p[i];
      nz |= (vv.x != 0.f) | (vv.y != 0.f) | (vv.z != 0.f) | (vv.w != 0.f);
    }
    int* acc = (int*)As;
    if (t == 0) acc[0] = 0;
    __syncthreads();
    unsigned long long m = __ballot(nz);
    if ((t & 63) == 0 && m) atomicOr(acc, 1);
    __syncthreads();
    if (t == 0) flags[(b * 16 + qt) * 32 + kt] = acc[0];
    return;
  }

  // ---------------- qkv GEMM block: XCD-pinned mt
  int mt = (u & 7) + 8 * (sg & 7);  // mt % 8 == XCD
  int nt = (sg >> 3) * 3 + (u >> 3);// 0..23
  int mat = nt >> 3;                // 0=Q 1=K 2=V
  int nbase = (nt & 7) * 128;
  const bf16* wmat = wt + (size_t)mat * DMODEL * DMODEL;
  const float* bias = (mat == 0) ? biasq : (mat == 1) ? biask : biasv;
  bf16* outp = (mat == 0) ? q : (mat == 1) ? k : v;

  int lane = t & 63, wid = t >> 6;
  int quad = lane >> 4, l16 = lane & 15;
  int wm = (wid & 1) * 64, wn = (wid >> 1) * 64;
  int xq = quad ^ (l16 & 7);        // swizzled chunk index

  floatx4 acc[4][4] = {};

  for (int kb = 0; kb < DMODEL; kb += BK) {
    __syncthreads();
#pragma unroll
    for (int p = 0; p < 4; p++) {
      int i2 = p * 256 + t;
      int row = i2 >> 3;
      int gch = (i2 ^ row) & 7;
      ASYNC_COPY16(xb + (size_t)(mt * 128 + row) * DMODEL + kb + gch * 8,
                   As + i2 * 8);
      ASYNC_COPY16(wmat + (size_t)(nbase + row) * DMODEL + kb + gch * 8,
                   Bs + i2 * 8);
    }
    __syncthreads();

#pragma unroll
    for (int kc = 0; kc < BK; kc += 32) {
      int xc = (kc >> 3) ^ xq;
      bf16x8 af[4], bfr[4];
#pragma unroll
      for (int mi = 0; mi < 4; mi++)
        af[mi] = *(const bf16x8*)(As + (wm + mi * 16 + l16) * BK + xc * 8);
#pragma unroll
      for (int ni = 0; ni < 4; ni++)
        bfr[ni] = *(const bf16x8*)(Bs + (wn + ni * 16 + l16) * BK + xc * 8);
      if (mat < 2) {   // transposed: D[n][m], col=l16=token
#pragma unroll
        for (int mi = 0; mi < 4; mi++)
#pragma unroll
          for (int ni = 0; ni < 4; ni++)
            acc[mi][ni] = __builtin_amdgcn_mfma_f32_16x16x32_bf16(
                bfr[ni], af[mi], acc[mi][ni], 0, 0, 0);
      } else {         // normal: D[m][n], col=l16=feature
#pragma unroll
        for (int mi = 0; mi < 4; mi++)
#pragma unroll
          for (int ni = 0; ni < 4; ni++)
            acc[mi][ni] = __builtin_amdgcn_mfma_f32_16x16x32_bf16(
                af[mi], bfr[ni], acc[mi][ni], 0, 0, 0);
      }
    }
  }

  int mg0 = mt * 128 + wm;
  if (mat < 2) {
    // Q/K: lane holds token s, 4 consecutive d in regs -> packed b64 stores
    float qscale = (mat == 0) ? 0.125f * LOG2E : 1.0f;
#pragma unroll
    for (int ni = 0; ni < 4; ni++) {
      int n0 = nbase + wn + ni * 16 + quad * 4;
      int h = n0 >> 6, d0 = n0 & 63;
      float4 bv4 = *(const float4*)(bias + n0);
#pragma unroll
      for (int mi = 0; mi < 4; mi++) {
        int m = mg0 + mi * 16 + l16;
        int b = m >> 11, s = m & 2047;
        bf16x4 pk;
        pk[0] = (bf16)((acc[mi][ni][0] + bv4.x) * qscale);
        pk[1] = (bf16)((acc[mi][ni][1] + bv4.y) * qscale);
        pk[2] = (bf16)((acc[mi][ni][2] + bv4.z) * qscale);
        pk[3] = (bf16)((acc[mi][ni][3] + bv4.w) * qscale);
        *(bf16x4*)(outp + (((size_t)(b * NH + h) * SQ + s) << 6) + d0) = pk;
      }
    }
  } else {
    // V: [B,H,DH,S], s contiguous in r -> packed b64 stores
#pragma unroll
    for (int ni = 0; ni < 4; ni++) {
      int n = nbase + wn + ni * 16 + l16;
      int h = n >> 6, d = n & 63;
      float bv_ = bias[n];
#pragma unroll
      for (int mi = 0; mi < 4; mi++) {
        int m0 = mg0 + mi * 16 + quad * 4;
        int b = m0 >> 11, s = m0 & 2047;
        bf16x4 pk;
#pragma unroll
        for (int r = 0; r < 4; r++) pk[r] = (bf16)(acc[mi][ni][r] + bv_);
        *(bf16x4*)(outp + (((size_t)(b * NH + h) * HD + d) << 11) + s) = pk;
      }
    }
  }
}

// ---------------------------------------------------------------- attention
// block = (b,h) x 128 q rows; 4 waves x 32 q rows; K tiles of 64 in LDS.
// S^T = K Q^T (per-lane softmax), one-pass exp2. Ks/Vs XOR-swizzled.
// REGISTER PREFETCH staging: tile k+1's K/V loaded into VGPRs right after
// tile k's barrier, in flight across the whole compute phase; ds_write at
// next loop top. Removes the global_load_lds vmcnt(0) drain stall.
#define PPAD 72   // P row stride in bf16 (144 B: 16B-aligned, ~2-way banks)
__global__ __launch_bounds__(256, 4) void attn(
    const bf16* __restrict__ Q,     // [64][2048][64], pre-scaled by 0.125*log2e
    const bf16* __restrict__ K,     // [64][2048][64]
    const bf16* __restrict__ Vt,    // [64][64][2048]
    const float* __restrict__ mask, // [4][2048][2048]
    const int* __restrict__ flags,  // [4][16][32]
    float* __restrict__ out) {      // [4][2048][1024]
  __shared__ bf16 Ks[64 * 64];      // [s][d], swizzled
  __shared__ bf16 Vs[64 * 64];      // [d][s], swizzled
  __shared__ bf16 P[4][32][PPAD];   // per-wave P^T stored as [q][k]

  int bh = blockIdx.x;              // 0..63 (all qt of one head on one XCD)
  int qt = blockIdx.y;
  int b = bh >> 4, h = bh & 15;
  int t = threadIdx.x, lane = t & 63, wid = t >> 6;
  int quad = lane >> 4, l16 = lane & 15;
  int q0 = qt * 128 + wid * 32;

  const bf16* Qp = Q + ((size_t)bh * SQ + q0) * HD;
  const bf16* Kp = K + (size_t)bh * SQ * HD;
  const bf16* Vp = Vt + (size_t)bh * HD * SQ;
  const float* mp = mask + ((size_t)b * SQ + q0) * SQ;
  const int* flg = flags + (b * 16 + qt) * 32;

  bf16x8 qa[2][2];
#pragma unroll
  for (int m = 0; m < 2; m++) {
    const bf16* qr = Qp + (size_t)(m * 16 + l16) * HD;
    qa[m][0] = *(const bf16x8*)(qr + quad * 8);
    qa[m][1] = *(const bf16x8*)(qr + 32 + quad * 8);
  }

  floatx4 o[2][4] = {};             // O^T[d][q]: col=l16=q, row=quad*4+r=d
  float li[2] = {0.f, 0.f};
  bf16* Pw = &P[wid][0][0];
  int xq = quad ^ (l16 & 7);

  // staging geometry: thread t owns LDS chunks t and t+256 of each tile
  int srow[2], sgch[2];
#pragma unroll
  for (int p = 0; p < 2; p++) {
    int sidx = p * 256 + t;
    srow[p] = sidx >> 3;
    sgch[p] = (sidx ^ srow[p]) & 7;
  }

  // prefetch tile 0
  float4 kreg[2], vreg[2];
#pragma unroll
  for (int p = 0; p < 2; p++) {
    kreg[p] = *(const float4*)(Kp + (size_t)srow[p] * HD + sgch[p] * 8);
    vreg[p] = *(const float4*)(Vp + (size_t)srow[p] * SQ + sgch[p] * 8);
  }

  for (int kb = 0, kti = 0; kb < SQ; kb += 64, kti++) {
    __syncthreads();                // prev tile's LDS reads done
#pragma unroll
    for (int p = 0; p < 2; p++) {   // regs (waited on here) -> LDS, b128
      int sidx = p * 256 + t;
      *(float4*)(Ks + sidx * 8) = kreg[p];
      *(float4*)(Vs + sidx * 8) = vreg[p];
    }
    __syncthreads();
    if (kti + 1 < 32) {             // issue next tile's loads; in flight across compute
      int kb2 = kb + 64;
#pragma unroll
      for (int p = 0; p < 2; p++) {
        kreg[p] = *(const float4*)(Kp + (size_t)(kb2 + srow[p]) * HD + sgch[p] * 8);
        vreg[p] = *(const float4*)(Vp + (size_t)srow[p] * SQ + kb2 + sgch[p] * 8);
      }
    }
    int flag = flg[kti];

    // Phase A: S^T for both m tiles
    float xs[2][4][4];
#pragma unroll
    for (int kt = 0; kt < 4; kt++) {
      const bf16* kr = Ks + (kt * 16 + l16) * 64;
      bf16x8 k0 = *(const bf16x8*)(kr + xq * 8);
      bf16x8 k1 = *(const bf16x8*)(kr + (xq ^ 4) * 8);
      floatx4 z0 = {}, z1 = {};
      z0 = __builtin_amdgcn_mfma_f32_16x16x32_bf16(k0, qa[0][0], z0, 0, 0, 0);
      z0 = __builtin_amdgcn_mfma_f32_16x16x32_bf16(k1, qa[0][1], z0, 0, 0, 0);
      z1 = __builtin_amdgcn_mfma_f32_16x16x32_bf16(k0, qa[1][0], z1, 0, 0, 0);
      z1 = __builtin_amdgcn_mfma_f32_16x16x32_bf16(k1, qa[1][1], z1, 0, 0, 0);
#pragma unroll
      for (int r = 0; r < 4; r++) { xs[0][kt][r] = z0[r]; xs[1][kt][r] = z1[r]; }
    }
    if (flag) {
#pragma unroll
      for (int m = 0; m < 2; m++)
#pragma unroll
        for (int kt = 0; kt < 4; kt++)
#pragma unroll
          for (int r = 0; r < 4; r++)
            xs[m][kt][r] = __builtin_fmaf(
                mp[(size_t)(m * 16 + l16) * SQ + kb + kt * 16 + quad * 4 + r],
                LOG2E, xs[m][kt][r]);
    }

    // Phase B: exp2 + per-lane partial sum; P^T -> LDS packed b64
#pragma unroll
    for (int m = 0; m < 2; m++) {
      float sum = 0.f;
#pragma unroll
      for (int kt = 0; kt < 4; kt++) {
        bf16x4 pk;
#pragma unroll
        for (int r = 0; r < 4; r++) {
          float e = __builtin_amdgcn_exp2f(xs[m][kt][r]);
          sum += e;
          pk[r] = (bf16)e;
        }
        *(bf16x4*)(Pw + (m * 16 + l16) * PPAD + kt * 16 + quad * 4) = pk;
      }
      li[m] += sum;
    }
    asm volatile("s_waitcnt lgkmcnt(0)" ::: "memory");
    bf16x8 pb[2][2];
#pragma unroll
    for (int m = 0; m < 2; m++) {
      pb[m][0] = *(const bf16x8*)(Pw + (m * 16 + l16) * PPAD + quad * 8);
      pb[m][1] = *(const bf16x8*)(Pw + (m * 16 + l16) * PPAD + 32 + quad * 8);
    }

    // Phase C: O^T += V^T x P^T
#pragma unroll
    for (int dt = 0; dt < 4; dt++) {
      const bf16* vr = Vs + (dt * 16 + l16) * 64;
      bf16x8 v0 = *(const bf16x8*)(vr + xq * 8);
      bf16x8 v1 = *(const bf16x8*)(vr + (xq ^ 4) * 8);
      o[0][dt] = __builtin_amdgcn_mfma_f32_16x16x32_bf16(v0, pb[0][0], o[0][dt], 0, 0, 0);
      o[0][dt] = __builtin_amdgcn_mfma_f32_16x16x32_bf16(v1, pb[0][1], o[0][dt], 0, 0, 0);
      o[1][dt] = __builtin_amdgcn_mfma_f32_16x16x32_bf16(v0, pb[1][0], o[1][dt], 0, 0, 0);
      o[1][dt] = __builtin_amdgcn_mfma_f32_16x16x32_bf16(v1, pb[1][1], o[1][dt], 0, 0, 0);
    }
  }
#pragma unroll
  for (int m = 0; m < 2; m++) {
    li[m] += __shfl_xor(li[m], 16, 64);
    li[m] += __shfl_xor(li[m], 32, 64);
  }
#pragma unroll
  for (int m = 0; m < 2; m++) {
    float inv = 1.0f / li[m];
    float* op = out + ((size_t)b * SQ + q0 + m * 16 + l16) * DMODEL + h * HD;
#pragma unroll
    for (int dt = 0; dt < 4; dt++)
#pragma unroll
      for (int r = 0; r < 4; r++)
        op[dt * 16 + quad * 4 + r] = o[m][dt][r] * inv;
  }
}

// ---------------------------------------------------------------- launcher
extern "C" void kernel_launch(void* const* d_in, const int* in_sizes, int n_in,
                              void* d_out, int out_size, void* d_ws, size_t ws_size,
                              hipStream_t stream) {
  (void)in_sizes; (void)n_in; (void)out_size; (void)ws_size;
  const float* hs   = (const float*)d_in[0];
  const float* mask = (const float*)d_in[1];
  const float* Wq   = (const float*)d_in[2];
  const float* bq   = (const float*)d_in[3];
  const float* Wk   = (const float*)d_in[4];
  const float* bk   = (const float*)d_in[5];
  const float* Wv   = (const float*)d_in[6];
  const float* bv   = (const float*)d_in[7];
  float* out = (float*)d_out;
  char* ws = (char*)d_ws;
  bf16* xb = (bf16*)(ws + XB_OFF);
  bf16* wt = (bf16*)(ws + WT_OFF);
  bf16* q  = (bf16*)(ws + Q_OFF);
  bf16* k  = (bf16*)(ws + K_OFF);
  bf16* v  = (bf16*)(ws + V_OFF);
  int* flg = (int*)(ws + FLG_OFF);

  prep<<<8192 + 3072, 256, 0, stream>>>(hs, xb, Wq, Wk, Wv, wt);
  qkv_mask<<<3584, 256, 0, stream>>>(xb, wt, bq, bk, bv, q, k, v, mask, flg);
  attn<<<dim3(64, 16), 256, 0, stream>>>(q, k, v, mask, flg, out);
}

// Round 9
// 295.754 us; speedup vs baseline: 1.2451x; 1.2451x over previous
//
#include <hip/hip_runtime.h>

typedef __bf16 bf16;
typedef __bf16 bf16x8 __attribute__((ext_vector_type(8)));
typedef __bf16 bf16x4 __attribute__((ext_vector_type(4)));
typedef float floatx4 __attribute__((ext_vector_type(4)));

typedef __attribute__((address_space(1))) void gvoid;
typedef __attribute__((address_space(3))) void lvoid;
#define ASYNC_COPY16(gp, lp) \
  __builtin_amdgcn_global_load_lds((gvoid*)(gp), (lvoid*)(lp), 16, 0, 0)

#define NB 4
#define SQ 2048
#define DMODEL 1024
#define NH 16
#define HD 64
#define MTOK (NB * SQ)   // 8192
#define LOG2E 1.44269504088896f

// workspace layout (bytes)
#define XB_OFF 0ull                        // bf16 X       [8192][1024]  16 MB
#define WT_OFF (16ull * 1024 * 1024)       // bf16 W^T x3  [3][1024][1024] 6 MB
#define Q_OFF  (22ull * 1024 * 1024)       // bf16 Q [64][2048][64]  16 MB (pre-scaled 0.125*log2e)
#define K_OFF  (38ull * 1024 * 1024)       // bf16 K [64][2048][64]  16 MB
#define V_OFF  (54ull * 1024 * 1024)       // bf16 V^T [64][64][2048] 16 MB
#define FLG_OFF (70ull * 1024 * 1024)      // int flags [4][16][32]   8 KB

// ------------------------------------------------- prep: convert X + transpose W
__global__ __launch_bounds__(256) void prep(
    const float* __restrict__ x, bf16* __restrict__ xb,
    const float* __restrict__ w0, const float* __restrict__ w1,
    const float* __restrict__ w2, bf16* __restrict__ wt) {
  __shared__ float tlds[32][33];
  int blk = blockIdx.x;
  int t = threadIdx.x;
  if (blk < 8192) {
    int i = blk * 256 + t;
    float4 v = ((const float4*)x)[i];
    bf16x4 o;
    o[0] = (bf16)v.x; o[1] = (bf16)v.y; o[2] = (bf16)v.z; o[3] = (bf16)v.w;
    ((bf16x4*)xb)[i] = o;
  } else {
    int tidx = blk - 8192;            // 0..3071
    int z = tidx >> 10;               // 0..2
    int rem = tidx & 1023;
    int kb = ((rem >> 5) & 31) * 32, nb = (rem & 31) * 32;
    const float* w = (z == 0) ? w0 : (z == 1) ? w1 : w2;
    bf16* out = wt + (size_t)z * DMODEL * DMODEL;
    int tx = t & 31, ty = t >> 5;     // 32 x 8
#pragma unroll
    for (int i = 0; i < 4; i++)
      tlds[ty + 8 * i][tx] = w[(size_t)(kb + ty + 8 * i) * DMODEL + nb + tx];
    __syncthreads();
#pragma unroll
    for (int i = 0; i < 4; i++)
      out[(size_t)(nb + ty + 8 * i) * DMODEL + kb + tx] = (bf16)tlds[tx][ty + 8 * i];
  }
}

// ---------------------------------------------------------------- QKV GEMM + mask scan (fused)
// 3584 blocks = 64 supergroups x 56. u<24 -> gemm (1536), u>=24 -> mask (2048).
// Supergroup keeps gemm:mask co-resident; mt%8 == blockIdx%8 pins each A-tile
// row to one XCD's L2. As/Bs XOR-swizzled; Q/K accumulate transposed.
#define BK 64
__global__ __launch_bounds__(256) void qkv_mask(
    const bf16* __restrict__ xb,   // [8192][1024]
    const bf16* __restrict__ wt,   // [3][1024 n][1024 k]
    const float* __restrict__ biasq, const float* __restrict__ biask,
    const float* __restrict__ biasv,
    bf16* __restrict__ q, bf16* __restrict__ k, bf16* __restrict__ v,
    const float* __restrict__ mask, int* __restrict__ flags) {
  __shared__ bf16 As[128 * BK];
  __shared__ bf16 Bs[128 * BK];

  int idx = blockIdx.x;
  int sg = idx / 56, u = idx % 56;   // 56 % 8 == 0 -> XCD = u % 8
  int t = threadIdx.x;

  if (u >= 24) {
    // ---------------- mask tile scan
    int midx = sg * 32 + (u - 24);    // 0..2047
    int kt = midx & 31, qt = (midx >> 5) & 15, b = midx >> 9;
    const float* mb = mask + ((size_t)b * SQ + qt * 128) * SQ + kt * 64;
    int row = t >> 1, half = t & 1;
    const float4* p = (const float4*)(mb + (size_t)row * SQ + half * 32);
    bool nz = false;
#pragma unroll
    for (int i = 0; i < 8; i++) {
      float4 vv = p[i];
      nz |= (vv.x != 0.f) | (vv.y != 0.f) | (vv.z != 0.f) | (vv.w != 0.f);
    }
    int* acc = (int*)As;
    if (t == 0) acc[0] = 0;
    __syncthreads();
    unsigned long long m = __ballot(nz);
    if ((t & 63) == 0 && m) atomicOr(acc, 1);
    __syncthreads();
    if (t == 0) flags[(b * 16 + qt) * 32 + kt] = acc[0];
    return;
  }

  // ---------------- qkv GEMM block: XCD-pinned mt
  int mt = (u & 7) + 8 * (sg & 7);  // mt % 8 == XCD
  int nt = (sg >> 3) * 3 + (u >> 3);// 0..23
  int mat = nt >> 3;                // 0=Q 1=K 2=V
  int nbase = (nt & 7) * 128;
  const bf16* wmat = wt + (size_t)mat * DMODEL * DMODEL;
  const float* bias = (mat == 0) ? biasq : (mat == 1) ? biask : biasv;
  bf16* outp = (mat == 0) ? q : (mat == 1) ? k : v;

  int lane = t & 63, wid = t >> 6;
  int quad = lane >> 4, l16 = lane & 15;
  int wm = (wid & 1) * 64, wn = (wid >> 1) * 64;
  int xq = quad ^ (l16 & 7);        // swizzled chunk index

  floatx4 acc[4][4] = {};

  for (int kb = 0; kb < DMODEL; kb += BK) {
    __syncthreads();
#pragma unroll
    for (int p = 0; p < 4; p++) {
      int i2 = p * 256 + t;
      int row = i2 >> 3;
      int gch = (i2 ^ row) & 7;
      ASYNC_COPY16(xb + (size_t)(mt * 128 + row) * DMODEL + kb + gch * 8,
                   As + i2 * 8);
      ASYNC_COPY16(wmat + (size_t)(nbase + row) * DMODEL + kb + gch * 8,
                   Bs + i2 * 8);
    }
    __syncthreads();

#pragma unroll
    for (int kc = 0; kc < BK; kc += 32) {
      int xc = (kc >> 3) ^ xq;
      bf16x8 af[4], bfr[4];
#pragma unroll
      for (int mi = 0; mi < 4; mi++)
        af[mi] = *(const bf16x8*)(As + (wm + mi * 16 + l16) * BK + xc * 8);
#pragma unroll
      for (int ni = 0; ni < 4; ni++)
        bfr[ni] = *(const bf16x8*)(Bs + (wn + ni * 16 + l16) * BK + xc * 8);
      if (mat < 2) {   // transposed: D[n][m], col=l16=token
#pragma unroll
        for (int mi = 0; mi < 4; mi++)
#pragma unroll
          for (int ni = 0; ni < 4; ni++)
            acc[mi][ni] = __builtin_amdgcn_mfma_f32_16x16x32_bf16(
                bfr[ni], af[mi], acc[mi][ni], 0, 0, 0);
      } else {         // normal: D[m][n], col=l16=feature
#pragma unroll
        for (int mi = 0; mi < 4; mi++)
#pragma unroll
          for (int ni = 0; ni < 4; ni++)
            acc[mi][ni] = __builtin_amdgcn_mfma_f32_16x16x32_bf16(
                af[mi], bfr[ni], acc[mi][ni], 0, 0, 0);
      }
    }
  }

  int mg0 = mt * 128 + wm;
  if (mat < 2) {
    // Q/K: lane holds token s, 4 consecutive d in regs -> packed b64 stores
    float qscale = (mat == 0) ? 0.125f * LOG2E : 1.0f;
#pragma unroll
    for (int ni = 0; ni < 4; ni++) {
      int n0 = nbase + wn + ni * 16 + quad * 4;
      int h = n0 >> 6, d0 = n0 & 63;
      float4 bv4 = *(const float4*)(bias + n0);
#pragma unroll
      for (int mi = 0; mi < 4; mi++) {
        int m = mg0 + mi * 16 + l16;
        int b = m >> 11, s = m & 2047;
        bf16x4 pk;
        pk[0] = (bf16)((acc[mi][ni][0] + bv4.x) * qscale);
        pk[1] = (bf16)((acc[mi][ni][1] + bv4.y) * qscale);
        pk[2] = (bf16)((acc[mi][ni][2] + bv4.z) * qscale);
        pk[3] = (bf16)((acc[mi][ni][3] + bv4.w) * qscale);
        *(bf16x4*)(outp + (((size_t)(b * NH + h) * SQ + s) << 6) + d0) = pk;
      }
    }
  } else {
    // V: [B,H,DH,S], s contiguous in r -> packed b64 stores
#pragma unroll
    for (int ni = 0; ni < 4; ni++) {
      int n = nbase + wn + ni * 16 + l16;
      int h = n >> 6, d = n & 63;
      float bv_ = bias[n];
#pragma unroll
      for (int mi = 0; mi < 4; mi++) {
        int m0 = mg0 + mi * 16 + quad * 4;
        int b = m0 >> 11, s = m0 & 2047;
        bf16x4 pk;
#pragma unroll
        for (int r = 0; r < 4; r++) pk[r] = (bf16)(acc[mi][ni][r] + bv_);
        *(bf16x4*)(outp + (((size_t)(b * NH + h) * HD + d) << 11) + s) = pk;
      }
    }
  }
}

// ---------------------------------------------------------------- attention
// block = (b,h) x 128 q rows; 4 waves x 32 q rows; K tiles of 64 staged in LDS
// via global_load_lds (round-7 known-good structure: the reg-prefetch variant
// spilled to scratch, +356 MB HBM writes — do not hold per-thread loads across
// the MFMA region). S^T = K Q^T (per-lane softmax), one-pass exp2, XOR-swizzle.
#define PPAD 72   // P row stride in bf16 (144 B: 16B-aligned, ~2-way banks)
__global__ __launch_bounds__(256, 4) void attn(
    const bf16* __restrict__ Q,     // [64][2048][64], pre-scaled by 0.125*log2e
    const bf16* __restrict__ K,     // [64][2048][64]
    const bf16* __restrict__ Vt,    // [64][64][2048]
    const float* __restrict__ mask, // [4][2048][2048]
    const int* __restrict__ flags,  // [4][16][32]
    float* __restrict__ out) {      // [4][2048][1024]
  __shared__ bf16 Ks[64 * 64];      // [s][d], swizzled
  __shared__ bf16 Vs[64 * 64];      // [d][s], swizzled
  __shared__ bf16 P[4][32][PPAD];   // per-wave P^T stored as [q][k]

  int bh = blockIdx.x;              // 0..63 (all qt of one head on one XCD)
  int qt = blockIdx.y;
  int b = bh >> 4, h = bh & 15;
  int t = threadIdx.x, lane = t & 63, wid = t >> 6;
  int quad = lane >> 4, l16 = lane & 15;
  int q0 = qt * 128 + wid * 32;

  const bf16* Qp = Q + ((size_t)bh * SQ + q0) * HD;
  const bf16* Kp = K + (size_t)bh * SQ * HD;
  const bf16* Vp = Vt + (size_t)bh * HD * SQ;
  const float* mp = mask + ((size_t)b * SQ + q0) * SQ;
  const int* flg = flags + (b * 16 + qt) * 32;

  bf16x8 qa[2][2];
#pragma unroll
  for (int m = 0; m < 2; m++) {
    const bf16* qr = Qp + (size_t)(m * 16 + l16) * HD;
    qa[m][0] = *(const bf16x8*)(qr + quad * 8);
    qa[m][1] = *(const bf16x8*)(qr + 32 + quad * 8);
  }

  floatx4 o[2][4] = {};             // O^T[d][q]: col=l16=q, row=quad*4+r=d
  float li[2] = {0.f, 0.f};
  bf16* Pw = &P[wid][0][0];
  int xq = quad ^ (l16 & 7);

  for (int kb = 0, kti = 0; kb < SQ; kb += 64, kti++) {
    __syncthreads();
#pragma unroll
    for (int p = 0; p < 2; p++) {
      int idx = p * 256 + t;        // 0..511
      int row = idx >> 3;
      int gch = (idx ^ row) & 7;
      ASYNC_COPY16(Kp + (size_t)(kb + row) * HD + gch * 8, Ks + idx * 8);
      ASYNC_COPY16(Vp + (size_t)row * SQ + kb + gch * 8, Vs + idx * 8);
    }
    __syncthreads();
    int flag = flg[kti];

    // Phase A: S^T for both m tiles
    float xs[2][4][4];
#pragma unroll
    for (int kt = 0; kt < 4; kt++) {
      const bf16* kr = Ks + (kt * 16 + l16) * 64;
      bf16x8 k0 = *(const bf16x8*)(kr + xq * 8);
      bf16x8 k1 = *(const bf16x8*)(kr + (xq ^ 4) * 8);
      floatx4 z0 = {}, z1 = {};
      z0 = __builtin_amdgcn_mfma_f32_16x16x32_bf16(k0, qa[0][0], z0, 0, 0, 0);
      z0 = __builtin_amdgcn_mfma_f32_16x16x32_bf16(k1, qa[0][1], z0, 0, 0, 0);
      z1 = __builtin_amdgcn_mfma_f32_16x16x32_bf16(k0, qa[1][0], z1, 0, 0, 0);
      z1 = __builtin_amdgcn_mfma_f32_16x16x32_bf16(k1, qa[1][1], z1, 0, 0, 0);
#pragma unroll
      for (int r = 0; r < 4; r++) { xs[0][kt][r] = z0[r]; xs[1][kt][r] = z1[r]; }
    }
    if (flag) {
#pragma unroll
      for (int m = 0; m < 2; m++)
#pragma unroll
        for (int kt = 0; kt < 4; kt++)
#pragma unroll
          for (int r = 0; r < 4; r++)
            xs[m][kt][r] = __builtin_fmaf(
                mp[(size_t)(m * 16 + l16) * SQ + kb + kt * 16 + quad * 4 + r],
                LOG2E, xs[m][kt][r]);
    }

    // Phase B: exp2 + per-lane partial sum; P^T -> LDS packed b64
#pragma unroll
    for (int m = 0; m < 2; m++) {
      float sum = 0.f;
#pragma unroll
      for (int kt = 0; kt < 4; kt++) {
        bf16x4 pk;
#pragma unroll
        for (int r = 0; r < 4; r++) {
          float e = __builtin_amdgcn_exp2f(xs[m][kt][r]);
          sum += e;
          pk[r] = (bf16)e;
        }
        *(bf16x4*)(Pw + (m * 16 + l16) * PPAD + kt * 16 + quad * 4) = pk;
      }
      li[m] += sum;
    }
    asm volatile("s_waitcnt lgkmcnt(0)" ::: "memory");
    bf16x8 pb[2][2];
#pragma unroll
    for (int m = 0; m < 2; m++) {
      pb[m][0] = *(const bf16x8*)(Pw + (m * 16 + l16) * PPAD + quad * 8);
      pb[m][1] = *(const bf16x8*)(Pw + (m * 16 + l16) * PPAD + 32 + quad * 8);
    }

    // Phase C: O^T += V^T x P^T
#pragma unroll
    for (int dt = 0; dt < 4; dt++) {
      const bf16* vr = Vs + (dt * 16 + l16) * 64;
      bf16x8 v0 = *(const bf16x8*)(vr + xq * 8);
      bf16x8 v1 = *(const bf16x8*)(vr + (xq ^ 4) * 8);
      o[0][dt] = __builtin_amdgcn_mfma_f32_16x16x32_bf16(v0, pb[0][0], o[0][dt], 0, 0, 0);
      o[0][dt] = __builtin_amdgcn_mfma_f32_16x16x32_bf16(v1, pb[0][1], o[0][dt], 0, 0, 0);
      o[1][dt] = __builtin_amdgcn_mfma_f32_16x16x32_bf16(v0, pb[1][0], o[1][dt], 0, 0, 0);
      o[1][dt] = __builtin_amdgcn_mfma_f32_16x16x32_bf16(v1, pb[1][1], o[1][dt], 0, 0, 0);
    }
  }
#pragma unroll
  for (int m = 0; m < 2; m++) {
    li[m] += __shfl_xor(li[m], 16, 64);
    li[m] += __shfl_xor(li[m], 32, 64);
  }
#pragma unroll
  for (int m = 0; m < 2; m++) {
    float inv = 1.0f / li[m];
    float* op = out + ((size_t)b * SQ + q0 + m * 16 + l16) * DMODEL + h * HD;
#pragma unroll
    for (int dt = 0; dt < 4; dt++)
#pragma unroll
      for (int r = 0; r < 4; r++)
        op[dt * 16 + quad * 4 + r] = o[m][dt][r] * inv;
  }
}

// ---------------------------------------------------------------- launcher
extern "C" void kernel_launch(void* const* d_in, const int* in_sizes, int n_in,
                              void* d_out, int out_size, void* d_ws, size_t ws_size,
                              hipStream_t stream) {
  (void)in_sizes; (void)n_in; (void)out_size; (void)ws_size;
  const float* hs   = (const float*)d_in[0];
  const float* mask = (const float*)d_in[1];
  const float* Wq   = (const float*)d_in[2];
  const float* bq   = (const float*)d_in[3];
  const float* Wk   = (const float*)d_in[4];
  const float* bk   = (const float*)d_in[5];
  const float* Wv   = (const float*)d_in[6];
  const float* bv   = (const float*)d_in[7];
  float* out = (float*)d_out;
  char* ws = (char*)d_ws;
  bf16* xb = (bf16*)(ws + XB_OFF);
  bf16* wt = (bf16*)(ws + WT_OFF);
  bf16* q  = (bf16*)(ws + Q_OFF);
  bf16* k  = (bf16*)(ws + K_OFF);
  bf16* v  = (bf16*)(ws + V_OFF);
  int* flg = (int*)(ws + FLG_OFF);

  prep<<<8192 + 3072, 256, 0, stream>>>(hs, xb, Wq, Wk, Wv, wt);
  qkv_mask<<<3584, 256, 0, stream>>>(xb, wt, bq, bk, bv, q, k, v, mask, flg);
  attn<<<dim3(64, 16), 256, 0, stream>>>(q, k, v, mask, flg, out);
}